// Round 2
// baseline (181.064 us; speedup 1.0000x reference)
//
#include <hip/hip_runtime.h>
#include <hip/hip_cooperative_groups.h>

namespace cg = cooperative_groups;

#define N 128
#define DIM 8192
#define NN (N * N)      // 16384
#define ZSPLIT 64
#define BDIM 512
#define NWF 8           // waves per block
#define GSTRIDE 130     // LDS gm row stride (fallback solver)
#define NSTR 65         // per-class LDS row stride: 65%32=1 -> conflict-free col reads

// ---------------- wave-sync helpers ----------------------------------------
__device__ __forceinline__ void wave_fence() {
    __threadfence_block();
    __builtin_amdgcn_wave_barrier();
}
__device__ __forceinline__ double embed_key(double v, int j) {
    long long b = __double_as_longlong(v);
    return __longlong_as_double((b & ~127LL) | (long long)j);
}

// ---------------- single cooperative mega-kernel ----------------------------
// 256 blocks x 512 threads, all co-resident (1 block/CU, ~77 KB LDS).
// Phase 1: d2 partials, 64x64 tiles, K-chunk 128 (A/B read 2x each).
// Phase 2: z-reduce + transform -> gm (blocks 0..63).
// Phase 3: per-class wave JV solver (wave 0 of blocks 0..63).
// Phase 4: block 0 sums class values + rare block-wide fallback.
__global__ __launch_bounds__(BDIM) void mega_kernel(const float* __restrict__ A,
                                                    const float* __restrict__ B,
                                                    const int* __restrict__ t1,
                                                    const int* __restrict__ t2,
                                                    float* __restrict__ d2p,
                                                    float* __restrict__ gm,
                                                    int* __restrict__ flagarr,
                                                    double* __restrict__ cls_val,
                                                    float* __restrict__ out) {
    union Shm {                                   // phase-disjoint overlay
        struct { float As[64][36]; float Bk[32][68]; } d2;   // phase 1, 17.9 KB
        float ncls[64 * NSTR];                               // phase 3, 16.6 KB
        float gml[N * GSTRIDE];                              // phase 4, 66.6 KB
    };
    __shared__ Shm sh;
    // phase 2
    __shared__ int bf;
    // phase 3 smalls
    __shared__ int rowl[64], coll[64], rcnt[64], ccnt[64], tasks64[64], clm[64];
    // phase 4 smalls
    __shared__ int lbl1[N], lbl2[N], rowlist[N], collist[N];
    __shared__ int rstart[65], cstart[65], rcur[64], ccur[64], bigtasks[65];
    __shared__ int nbig_s, flag_s, jfin_s;
    __shared__ double ub[N + 1], vbp[N + 1], minvb[N + 1];
    __shared__ int pb[N + 1], wayb[N + 1], usedb[N + 1];
    __shared__ double redv[NWF];
    __shared__ int redi[NWF];
    __shared__ double big_total, small_sum;

    const int tid = threadIdx.x;
    cg::grid_group grid = cg::this_grid();

    // =================== Phase 1: d2 partials ===============================
    {
        const int bz = blockIdx.x & 63;           // K chunk (128 wide)
        const int bi = (blockIdx.x >> 6) & 1;     // row tile
        const int bj = (blockIdx.x >> 7) & 1;     // col tile
        const int row0 = bi * 64, col0 = bj * 64;
        const int kbase = bz * 128;
        const int tx = tid & 15, ty = tid >> 4;   // ty 0..31
        const int lr = tid >> 3, lq = tid & 7;    // staging coords
        float a0[4] = {0.f, 0.f, 0.f, 0.f}, a1[4] = {0.f, 0.f, 0.f, 0.f};

        for (int it = 0; it < 4; ++it) {          // k-sub chunks of 32
            const int k0 = kbase + it * 32;
            __syncthreads();
            *(float4*)&sh.d2.As[lr][lq * 4] = *(const float4*)&A[(row0 + lr) * DIM + k0 + lq * 4];
            float4 b4 = *(const float4*)&B[(col0 + lr) * DIM + k0 + lq * 4];
            sh.d2.Bk[lq * 4 + 0][lr] = b4.x;
            sh.d2.Bk[lq * 4 + 1][lr] = b4.y;
            sh.d2.Bk[lq * 4 + 2][lr] = b4.z;
            sh.d2.Bk[lq * 4 + 3][lr] = b4.w;
            __syncthreads();
            #pragma unroll
            for (int kk = 0; kk < 32; kk += 4) {
                float x0[4], x1[4];
                *(float4*)x0 = *(const float4*)&sh.d2.As[2 * ty][kk];
                *(float4*)x1 = *(const float4*)&sh.d2.As[2 * ty + 1][kk];
                #pragma unroll
                for (int q = 0; q < 4; ++q) {
                    float y[4];
                    *(float4*)y = *(const float4*)&sh.d2.Bk[kk + q][tx * 4];
                    #pragma unroll
                    for (int c = 0; c < 4; ++c) {
                        float d0 = x0[q] - y[c]; a0[c] = fmaf(d0, d0, a0[c]);
                        float d1 = x1[q] - y[c]; a1[c] = fmaf(d1, d1, a1[c]);
                    }
                }
            }
        }
        float* dst = d2p + bz * NN;
        const int o0 = (row0 + 2 * ty) * N + col0 + tx * 4;
        *(float4*)&dst[o0]     = *(float4*)a0;
        *(float4*)&dst[o0 + N] = *(float4*)a1;
    }
    grid.sync();

    // =================== Phase 2: reduce + transform ========================
    {
        if (tid == 0) bf = 0;
        __syncthreads();
        const bool active = (blockIdx.x < 64) && (tid < 256);
        bool bad = false;
        if (active) {
            const int o = blockIdx.x * 256 + tid;
            const float* p = d2p + o;
            float s0 = 0.f, s1 = 0.f, s2 = 0.f, s3 = 0.f, s4 = 0.f, s5 = 0.f, s6 = 0.f, s7 = 0.f;
            #pragma unroll
            for (int z = 0; z < ZSPLIT; z += 8) {
                s0 += p[(z + 0) * NN]; s1 += p[(z + 1) * NN];
                s2 += p[(z + 2) * NN]; s3 += p[(z + 3) * NN];
                s4 += p[(z + 4) * NN]; s5 += p[(z + 5) * NN];
                s6 += p[(z + 6) * NN]; s7 += p[(z + 7) * NN];
            }
            float s = ((s0 + s1) + (s2 + s3)) + ((s4 + s5) + (s6 + s7));
            const int i = o >> 7, j = o & 127;
            const int l1 = t1[i], l2 = t2[j];
            const bool same = (l1 == l2);
            float g = same ? fmaxf(s, 0.f) : fmaxf(200.f - s, 0.f);
            gm[o] = g;
            bad = (!same && g > 0.f) || l1 < 0 || l1 > 63 || l2 < 0 || l2 > 63;
        }
        unsigned long long m = __ballot(bad);
        if ((tid & 63) == 0 && m) atomicOr(&bf, 1);
        __syncthreads();
        if (blockIdx.x < 64 && tid == 0) flagarr[blockIdx.x] = bf;
    }
    grid.sync();

    // =================== Phase 3: per-class wave JV solver ==================
    // wave 0 of blocks 0..63 only; other waves fall through to grid sync.
    if (blockIdx.x < 64 && tid < 64) {
        const int lane = tid;
        const int l1a = t1[lane] & 63, l1b = t1[lane + 64] & 63;
        const int l2a = t2[lane] & 63, l2b = t2[lane + 64] & 63;
        const int fl  = flagarr[lane];
        rcnt[lane] = 0; ccnt[lane] = 0;
        wave_fence();
        atomicAdd(&rcnt[l1a], 1); atomicAdd(&rcnt[l1b], 1);
        atomicAdd(&ccnt[l2a], 1); atomicAdd(&ccnt[l2b], 1);
        wave_fence();
        const bool flag = (__ballot(fl != 0) != 0ull);
        int ntasks;
        {
            int R = rcnt[lane], C = ccnt[lane];
            bool small = (!flag) && (R > 0) && (C > 0) && (R <= 64) && (C <= 64);
            unsigned long long ms = __ballot(small);
            if (small) tasks64[__popcll(ms & ((1ull << lane) - 1))] = lane;
            ntasks = (int)__popcll(ms);
        }
        wave_fence();
        const bool have = ((int)blockIdx.x < ntasks);
        double val = 0.0;
        if (have) {
            const int c = tasks64[blockIdx.x];
            // compact this class's row/col index lists via ballots
            const unsigned long long mlt = (1ull << lane) - 1;
            unsigned long long b1 = __ballot(l1a == c);
            unsigned long long b2 = __ballot(l1b == c);
            if (l1a == c) rowl[__popcll(b1 & mlt)] = lane;
            if (l1b == c) rowl[__popcll(b1) + __popcll(b2 & mlt)] = lane + 64;
            const int Rn = (int)(__popcll(b1) + __popcll(b2));
            unsigned long long c1 = __ballot(l2a == c);
            unsigned long long c2 = __ballot(l2b == c);
            if (l2a == c) coll[__popcll(c1 & mlt)] = lane;
            if (l2b == c) coll[__popcll(c1) + __popcll(c2 & mlt)] = lane + 64;
            const int Cn = (int)(__popcll(c1) + __popcll(c2));
            wave_fence();

            // stage normalized (n_ <= m_) class submatrix
            const bool T  = (Rn > Cn);
            const int n_  = T ? Cn : Rn;
            const int m_  = T ? Rn : Cn;
            const int tot = n_ * m_;
            for (int e = lane; e < tot; e += 64) {
                int i = e / m_, j = e - i * m_;
                int gr = T ? rowl[j] : rowl[i];
                int gc = T ? coll[i] : coll[j];
                sh.ncls[i * NSTR + j] = gm[gr * N + gc];
            }
            wave_fence();

            const int W = (m_ <= 16) ? 16 : (m_ <= 32 ? 32 : 64);
            const bool cA = (lane < m_), rA = (lane < n_);

            // row reduction: u = -max_j cls(row=lane, j)
            double u = 0.0;
            if (rA) {
                float mx = 0.f;
                const float* row = &sh.ncls[lane * NSTR];
                for (int j = 0; j < m_; ++j) mx = fmaxf(mx, row[j]);
                u = -(double)mx;
            }
            // col reduction: v = min_i (-cls(i, col=lane) - u_i)
            double v = 1e30;
            for (int i = 0; i < n_; ++i) {
                double ui = __shfl(u, i, 64);
                if (cA) v = fmin(v, -(double)sh.ncls[i * NSTR + lane] - ui);
            }
            // greedy tight assignment
            if (cA) clm[lane] = 0x7fffffff;
            wave_fence();
            int jc = -1;
            for (int j = 0; j < m_; ++j) {
                double vj = __shfl(v, j, 64);
                if (rA && jc < 0) {
                    double s = -(double)sh.ncls[lane * NSTR + j] - u - vj;
                    if (s < 1e-7) jc = j;
                }
            }
            if (rA && jc >= 0) atomicMin(&clm[jc], lane);
            wave_fence();
            int p = -1;
            if (cA && clm[lane] != 0x7fffffff) p = clm[lane];
            bool rowm = (rA && jc >= 0 && clm[jc] == lane);

            // augmentation phases (JV)
            for (int ir = 0; ir < n_; ++ir) {
                if (__shfl(rowm ? 1 : 0, ir, 64)) continue;
                double minv = 1e30, markD = -1.0, ent = -1.0;
                bool used = false; int way = -2;
                if (rA && lane == ir) ent = 0.0;
                double D = 0.0;
                int i0 = ir, jprev = -1;
                int guard = 2 * m_ + 8;
                while (guard-- > 0) {
                    double ui = __shfl(u, i0, 64);
                    if (cA && !used) {
                        double cand = D - ui - (double)sh.ncls[i0 * NSTR + lane] - v;
                        if (cand < minv) { minv = cand; way = jprev; }
                    }
                    double kd = (cA && !used) ? embed_key(minv, lane) : 1e30;
                    for (int o = 1; o < W; o <<= 1) kd = fmin(kd, __shfl_xor(kd, o, 64));
                    long long kb = __double_as_longlong(kd);
                    int j1 = (int)(kb & 127);
                    double Dn = __longlong_as_double(kb & ~127LL);
                    if (Dn > 1e29) break;
                    D = Dn;
                    int i1 = __shfl(p, j1, 64);
                    if (i1 < 0) {                 // free col: augment along way[]
                        int jj = j1;
                        while (true) {
                            int wp = __shfl(way, jj, 64);
                            int pn = (wp < 0) ? ir : __shfl(p, wp, 64);
                            if (cA && lane == jj) p = pn;
                            if (wp < 0) break;
                            jj = wp;
                        }
                        if (rA && lane == ir) rowm = true;
                        break;
                    }
                    if (cA && lane == j1) { used = true; markD = D; }
                    if (rA && lane == i1) ent = D;
                    jprev = j1; i0 = i1;
                }
                if (rA && ent   >= 0.0) u += D - ent;
                if (cA && markD >= 0.0) v -= D - markD;
            }

            // class value
            if (cA && p >= 0) val = (double)sh.ncls[p * NSTR + lane];
            #pragma unroll
            for (int o = 1; o < 64; o <<= 1) val += __shfl_xor(val, o, 64);
        }
        if (lane == 0) cls_val[blockIdx.x] = have ? val : 0.0;
    }
    grid.sync();

    // =================== Phase 4: finalize (block 0 only) ===================
    if (blockIdx.x != 0) return;

    if (tid < 64) { rcnt[tid] = 0; ccnt[tid] = 0; rcur[tid] = 0; ccur[tid] = 0; }
    if (tid == 0) { nbig_s = 0; flag_s = 0; big_total = 0.0; }
    if (tid < N)  { lbl1[tid] = t1[tid]; lbl2[tid] = t2[tid]; }
    __syncthreads();
    if (tid < 64 && flagarr[tid]) atomicOr(&flag_s, 1);
    if (tid < N) {
        atomicAdd(&rcnt[lbl1[tid] & 63], 1);
        atomicAdd(&ccnt[lbl2[tid] & 63], 1);
    }
    double sv = (tid < 64) ? cls_val[tid] : 0.0;
    __syncthreads();
    if (tid < 64) {
        int rs_ = rcnt[tid], cs_ = ccnt[tid];
        #pragma unroll
        for (int o = 1; o < 64; o <<= 1) {
            int tr = __shfl_up(rs_, o, 64);
            int tc = __shfl_up(cs_, o, 64);
            if (tid >= o) { rs_ += tr; cs_ += tc; }
        }
        rstart[tid + 1] = rs_;
        cstart[tid + 1] = cs_;
        if (tid == 0) { rstart[0] = 0; cstart[0] = 0; }
        if (!flag_s) {
            int R = rcnt[tid], C = ccnt[tid];
            bool big = (R > 0) && (C > 0) && ((R > 64) || (C > 64));
            unsigned long long mb = __ballot(big);
            if (big) bigtasks[__popcll(mb & ((1ull << tid) - 1))] = tid;
            if (tid == 0) nbig_s = __popcll(mb);
        } else if (tid == 0) { nbig_s = 1; bigtasks[0] = -1; }
        #pragma unroll
        for (int o = 1; o < 64; o <<= 1) sv += __shfl_xor(sv, o, 64);
        if (tid == 0) small_sum = sv;
    }
    __syncthreads();

    const int nbig = nbig_s;
    if (nbig > 0) {
        if (tid < N) {       // counting-sort scatter
            int l1 = lbl1[tid] & 63;
            int p = atomicAdd(&rcur[l1], 1);
            rowlist[rstart[l1] + p] = tid;
            int l2 = lbl2[tid] & 63;
            int q = atomicAdd(&ccur[l2], 1);
            collist[cstart[l2] + q] = tid;
        }
        __syncthreads();
        #pragma unroll
        for (int pch = 0; pch < 32; ++pch) {
            int e = tid + pch * BDIM;
            int i = e >> 7, j = e & 127;
            sh.gml[i * GSTRIDE + j] = gm[rowlist[i] * N + collist[j]];
        }
        __syncthreads();

        for (int bt = 0; bt < nbig; ++bt) {
            const int c = bigtasks[bt];
            int Rn, Cn, rs, cs;
            if (c < 0) { Rn = N; Cn = N; rs = 0; cs = 0; }
            else { Rn = rcnt[c]; Cn = ccnt[c]; rs = rstart[c]; cs = cstart[c]; }
            const bool T = (Rn > Cn);
            const int n_ = T ? Cn : Rn, m_ = T ? Rn : Cn;
            const int rstep = T ? 1 : GSTRIDE;
            const int cstep = T ? GSTRIDE : 1;
            const int rb00 = T ? cs : rs * GSTRIDE;
            const int ob00 = T ? rs * GSTRIDE : cs;
            auto cost = [&](int i, int j) -> double {
                return -(double)sh.gml[rb00 + i * rstep + ob00 + j * cstep];
            };
            for (int x = tid; x <= m_; x += BDIM) { vbp[x] = 0.0; pb[x] = 0; }
            for (int x = tid; x <= n_; x += BDIM) { ub[x] = 0.0; }
            __syncthreads();
            for (int i = 1; i <= n_; ++i) {
                if (tid == 0) pb[0] = i;
                for (int x = tid; x <= m_; x += BDIM) { minvb[x] = 1e300; usedb[x] = 0; }
                __syncthreads();
                int j0 = 0;
                int guard = 2 * m_ + 8;
                while (guard-- > 0) {
                    if (tid == 0) usedb[j0] = 1;
                    __syncthreads();
                    const int i0 = pb[j0];
                    double dl = 1e300; int jl = 0;
                    if (tid < m_) {
                        int j = tid + 1;
                        if (!usedb[j]) {
                            double cur = cost(i0 - 1, j - 1) - ub[i0] - vbp[j];
                            if (cur < minvb[j]) { minvb[j] = cur; wayb[j] = j0; }
                            dl = minvb[j]; jl = j;
                        }
                    }
                    double rv = dl; int ri = jl;
                    #pragma unroll
                    for (int o = 32; o > 0; o >>= 1) {
                        double ov = __shfl_down(rv, o, 64);
                        int oi2 = __shfl_down(ri, o, 64);
                        if (ov < rv) { rv = ov; ri = oi2; }
                    }
                    if ((tid & 63) == 0) { redv[tid >> 6] = rv; redi[tid >> 6] = ri; }
                    __syncthreads();
                    if (tid == 0) {
                        double bd = 1e300; int bj = 0;
                        for (int q = 0; q < NWF; ++q) if (redv[q] < bd) { bd = redv[q]; bj = redi[q]; }
                        redv[0] = bd; redi[0] = bj;
                    }
                    __syncthreads();
                    const double delta = redv[0];
                    const int j1 = redi[0];
                    if (tid < m_) {
                        int j = tid + 1;
                        if (usedb[j]) { ub[pb[j]] += delta; vbp[j] -= delta; }
                        else          { minvb[j] -= delta; }
                    }
                    if (tid == 0) ub[pb[0]] += delta;
                    __syncthreads();
                    j0 = j1;
                    if (pb[j0] == 0) break;
                }
                if (tid == 0) jfin_s = j0;
                __syncthreads();
                if (tid == 0) {
                    int jj = jfin_s;
                    while (jj) { int jp = wayb[jj]; pb[jj] = pb[jp]; jj = jp; }
                }
                __syncthreads();
            }
            double bl = 0.0;
            if (tid < m_) { int j = tid + 1; if (pb[j] != 0) bl = -cost(pb[j] - 1, j - 1); }
            #pragma unroll
            for (int o = 32; o > 0; o >>= 1) bl += __shfl_down(bl, o, 64);
            if ((tid & 63) == 0) redv[tid >> 6] = bl;
            __syncthreads();
            if (tid == 0) { double s = 0; for (int q = 0; q < NWF; ++q) s += redv[q]; big_total += s; }
            __syncthreads();
        }
    }

    if (tid == 0) out[0] = (float)((small_sum + big_total) / (double)N);
}

extern "C" void kernel_launch(void* const* d_in, const int* in_sizes, int n_in,
                              void* d_out, int out_size, void* d_ws, size_t ws_size,
                              hipStream_t stream) {
    const float* A  = (const float*)d_in[0];
    const float* B  = (const float*)d_in[1];
    const int*   t1 = (const int*)d_in[2];
    const int*   t2 = (const int*)d_in[3];
    float* out = (float*)d_out;
    float* d2p = (float*)d_ws;                        // [64][16384] partials, 4 MB
    float* gm  = (float*)d_ws + ZSPLIT * NN;          // [128][128] gm, 64 KB
    int*   flagarr = (int*)(gm + NN);                 // [64] cross-label flags
    double* cls_val = (double*)(flagarr + 64);        // [64] per-class values

    void* args[] = {(void*)&A, (void*)&B, (void*)&t1, (void*)&t2,
                    (void*)&d2p, (void*)&gm, (void*)&flagarr,
                    (void*)&cls_val, (void*)&out};
    hipLaunchCooperativeKernel((const void*)mega_kernel, dim3(256), dim3(BDIM),
                               args, 0, stream);
}

// Round 3
// 98.529 us; speedup vs baseline: 1.8377x; 1.8377x over previous
//
#include <hip/hip_runtime.h>

#define N 128
#define DIM 8192
#define NN (N * N)      // 16384
#define ZSPLIT 64
#define NWF 4           // waves in fused kernel (256 threads)
#define GSTRIDE 130     // LDS gm row stride (fallback solver)
#define NSTR 65         // per-class LDS row stride: 65%32=1 -> conflict-free col reads

// ---------------- wave-sync helpers ----------------------------------------
__device__ __forceinline__ void wave_fence() {
    __threadfence_block();
    __builtin_amdgcn_wave_barrier();
}
__device__ __forceinline__ double embed_key(double v, int j) {
    long long b = __double_as_longlong(v);
    return __longlong_as_double((b & ~127LL) | (long long)j);
}

// ---------------- Stage 1: dot partials + norm partials (split-K) -----------
// grid (4,4,64): 32x32 tile, K-chunk 128. 2x2 register tile per thread.
// Stores DOT products; d2 is assembled downstream as sqA + sqB - 2*dot
// (the reference's own formula). Norm partials from bi==0 / bj==0 blocks.
__global__ __launch_bounds__(256) void d2_partial(const float* __restrict__ A,
                                                  const float* __restrict__ B,
                                                  float* __restrict__ d2p,
                                                  float* __restrict__ sqAp,
                                                  float* __restrict__ sqBp,
                                                  int* __restrict__ ctr) {
    __shared__ float As[32][68];
    __shared__ float Bk[64][36];
    const int tid = threadIdx.x;
    const int bi = blockIdx.x, bj = blockIdx.y, bz = blockIdx.z;
    const int tx = tid & 15, ty = tid >> 4;
    const int row0 = bi * 32, col0 = bj * 32;
    const int kbase = bz * 128;

    if (bi == 0 && bj == 0 && bz == 0 && tid == 0) *ctr = 0;

    // norm-partial prelude (outside hot loop; only edge blocks)
    if (bj == 0) {
        const int r = tid >> 3, seg = tid & 7;
        const float* pa = &A[(row0 + r) * DIM + kbase + seg * 16];
        float s = 0.f;
        #pragma unroll
        for (int u = 0; u < 4; ++u) {
            float4 v = *(const float4*)&pa[u * 4];
            s = fmaf(v.x, v.x, fmaf(v.y, v.y, fmaf(v.z, v.z, fmaf(v.w, v.w, s))));
        }
        #pragma unroll
        for (int o = 1; o < 8; o <<= 1) s += __shfl_xor(s, o, 64);
        if (seg == 0) sqAp[bz * 128 + row0 + r] = s;
    }
    if (bi == 0) {
        const int r = tid >> 3, seg = tid & 7;
        const float* pb = &B[(col0 + r) * DIM + kbase + seg * 16];
        float s = 0.f;
        #pragma unroll
        for (int u = 0; u < 4; ++u) {
            float4 v = *(const float4*)&pb[u * 4];
            s = fmaf(v.x, v.x, fmaf(v.y, v.y, fmaf(v.z, v.z, fmaf(v.w, v.w, s))));
        }
        #pragma unroll
        for (int o = 1; o < 8; o <<= 1) s += __shfl_xor(s, o, 64);
        if (seg == 0) sqBp[bz * 128 + col0 + r] = s;
    }

    float a00 = 0.f, a01 = 0.f, a10 = 0.f, a11 = 0.f;
    for (int it = 0; it < 2; ++it) {
        const int k0 = kbase + it * 64;
        __syncthreads();
        #pragma unroll
        for (int s = 0; s < 2; ++s) {
            int e = tid + s * 256;
            int r = e >> 4, q = e & 15;
            *(float4*)&As[r][q * 4] = *(const float4*)&A[(row0 + r) * DIM + k0 + q * 4];
        }
        #pragma unroll
        for (int s = 0; s < 2; ++s) {
            int r = tid & 31;
            int kq = (tid >> 5) + s * 8;
            float4 b4 = *(const float4*)&B[(col0 + r) * DIM + k0 + kq * 4];
            Bk[kq * 4 + 0][r] = b4.x;
            Bk[kq * 4 + 1][r] = b4.y;
            Bk[kq * 4 + 2][r] = b4.z;
            Bk[kq * 4 + 3][r] = b4.w;
        }
        __syncthreads();
        #pragma unroll
        for (int kk = 0; kk < 64; kk += 4) {
            float x0[4], x1[4];
            *(float4*)x0 = *(const float4*)&As[2 * ty][kk];
            *(float4*)x1 = *(const float4*)&As[2 * ty + 1][kk];
            float y[4][2];
            #pragma unroll
            for (int q = 0; q < 4; ++q)
                *(float2*)y[q] = *(const float2*)&Bk[kk + q][2 * tx];
            #pragma unroll
            for (int q = 0; q < 4; ++q) {
                a00 = fmaf(x0[q], y[q][0], a00);
                a01 = fmaf(x0[q], y[q][1], a01);
                a10 = fmaf(x1[q], y[q][0], a10);
                a11 = fmaf(x1[q], y[q][1], a11);
            }
        }
    }
    const int o0 = (row0 + 2 * ty) * N + col0 + 2 * tx;
    float* dst = d2p + bz * NN;
    *(float2*)&dst[o0]     = make_float2(a00, a01);
    *(float2*)&dst[o0 + N] = make_float2(a10, a11);
}

// ---------------- Stage 2: fused reduce + per-class solve + finalize --------
// 64 blocks x 256 threads.
//  A: z-reduce dot partials + norms -> gm + flag (this block's 256-elem slice)
//  B: class decomposition (wave 0), gather own class submatrix from d2p,
//     wave-0 JV solver -> cls_val[blk]
//  C: last block (device atomic counter) sums cls_val + rare fallback.
__global__ __launch_bounds__(256) void reduce_solve(const float* __restrict__ d2p,
                                                    const float* __restrict__ sqAp,
                                                    const float* __restrict__ sqBp,
                                                    const int* __restrict__ t1,
                                                    const int* __restrict__ t2,
                                                    float* __restrict__ gm,
                                                    int* __restrict__ flagarr,
                                                    double* __restrict__ cls_val,
                                                    int* __restrict__ ctr,
                                                    float* __restrict__ out) {
    union Shm {
        float ncls[64 * NSTR];      // phase B, 16.6 KB
        float gml[N * GSTRIDE];     // phase C fallback, 66.6 KB
    };
    __shared__ Shm sh;
    __shared__ float sqA_l[128], sqB_l[128];
    __shared__ int bf;
    __shared__ int rowl[64], coll[64], rcnt[64], ccnt[64], tasks64[64], clm[64];
    __shared__ int sT, sn, sm, shave;
    __shared__ int isLast;
    // finalize scratch
    __shared__ int lbl1[N], lbl2[N], rowlist[N], collist[N];
    __shared__ int rstart[65], cstart[65], rcur[64], ccur[64], bigtasks[65];
    __shared__ int nbig_s, flag_s, jfin_s;
    __shared__ double ub[N + 1], vbp[N + 1], minvb[N + 1];
    __shared__ int pb[N + 1], wayb[N + 1], usedb[N + 1];
    __shared__ double redv[NWF];
    __shared__ int redi[NWF];
    __shared__ double big_total, small_sum;

    const int tid = threadIdx.x;
    const int blk = blockIdx.x;

    // ---------------- Phase A: reduce + transform ---------------------------
    if (tid == 0) bf = 0;
    {   // stage full norm vectors (needed by A combine and B gather)
        const int c = tid & 127;
        const float* src = (tid < 128) ? (sqBp + c) : (sqAp + c);
        float t0 = 0.f, t1_ = 0.f, t2_ = 0.f, t3 = 0.f, t4 = 0.f, t5 = 0.f, t6 = 0.f, t7 = 0.f;
        #pragma unroll
        for (int z = 0; z < ZSPLIT; z += 8) {
            t0 += src[(z + 0) * 128]; t1_ += src[(z + 1) * 128];
            t2_ += src[(z + 2) * 128]; t3 += src[(z + 3) * 128];
            t4 += src[(z + 4) * 128]; t5 += src[(z + 5) * 128];
            t6 += src[(z + 6) * 128]; t7 += src[(z + 7) * 128];
        }
        float s = ((t0 + t1_) + (t2_ + t3)) + ((t4 + t5) + (t6 + t7));
        if (tid < 128) sqB_l[c] = s; else sqA_l[c] = s;
    }
    const int o = blk * 256 + tid;
    const int gi = o >> 7, gj = o & 127;
    float dot;
    {
        const float* p = d2p + o;
        float s0 = 0.f, s1 = 0.f, s2 = 0.f, s3 = 0.f, s4 = 0.f, s5 = 0.f, s6 = 0.f, s7 = 0.f;
        #pragma unroll
        for (int z = 0; z < ZSPLIT; z += 8) {
            s0 += p[(z + 0) * NN]; s1 += p[(z + 1) * NN];
            s2 += p[(z + 2) * NN]; s3 += p[(z + 3) * NN];
            s4 += p[(z + 4) * NN]; s5 += p[(z + 5) * NN];
            s6 += p[(z + 6) * NN]; s7 += p[(z + 7) * NN];
        }
        dot = ((s0 + s1) + (s2 + s3)) + ((s4 + s5) + (s6 + s7));
    }
    __syncthreads();
    {
        const float s = sqA_l[gi] + sqB_l[gj] - 2.f * dot;
        const int l1 = t1[gi], l2 = t2[gj];
        const bool same = (l1 == l2);
        float g = same ? fmaxf(s, 0.f) : fmaxf(200.f - s, 0.f);
        gm[o] = g;
        bool bad = (!same && g > 0.f) || l1 < 0 || l1 > 63 || l2 < 0 || l2 > 63;
        unsigned long long m = __ballot(bad);
        if ((tid & 63) == 0 && m) atomicOr(&bf, 1);
    }
    __syncthreads();
    if (tid == 0) flagarr[blk] = bf;

    // ---------------- Phase B: decomposition + class solve ------------------
    if (tid < 64) {
        const int lane = tid;
        const int l1a = t1[lane] & 63, l1b = t1[lane + 64] & 63;
        const int l2a = t2[lane] & 63, l2b = t2[lane + 64] & 63;
        rcnt[lane] = 0; ccnt[lane] = 0;
        wave_fence();
        atomicAdd(&rcnt[l1a], 1); atomicAdd(&rcnt[l1b], 1);
        atomicAdd(&ccnt[l2a], 1); atomicAdd(&ccnt[l2b], 1);
        wave_fence();
        int ntasks;
        {
            int R = rcnt[lane], C = ccnt[lane];
            bool small = (R > 0) && (C > 0) && (R <= 64) && (C <= 64);
            unsigned long long ms = __ballot(small);
            if (small) tasks64[__popcll(ms & ((1ull << lane) - 1))] = lane;
            ntasks = (int)__popcll(ms);
        }
        wave_fence();
        const bool have = (blk < ntasks);
        if (have) {
            const int c = tasks64[blk];
            const unsigned long long mlt = (1ull << lane) - 1;
            unsigned long long b1 = __ballot(l1a == c);
            unsigned long long b2 = __ballot(l1b == c);
            if (l1a == c) rowl[__popcll(b1 & mlt)] = lane;
            if (l1b == c) rowl[__popcll(b1) + __popcll(b2 & mlt)] = lane + 64;
            const int Rn = (int)(__popcll(b1) + __popcll(b2));
            unsigned long long c1 = __ballot(l2a == c);
            unsigned long long c2 = __ballot(l2b == c);
            if (l2a == c) coll[__popcll(c1 & mlt)] = lane;
            if (l2b == c) coll[__popcll(c1) + __popcll(c2 & mlt)] = lane + 64;
            const int Cn = (int)(__popcll(c1) + __popcll(c2));
            if (lane == 0) {
                const bool T = (Rn > Cn);
                sT = T ? 1 : 0;
                sn = T ? Cn : Rn;
                sm = T ? Rn : Cn;
            }
        }
        if (lane == 0) shave = have ? 1 : 0;
    }
    __syncthreads();

    if (shave) {   // gather class submatrix from d2p (4 lanes per entry)
        const int n_ = sn, m_ = sm, T = sT;
        const int tot = n_ * m_;
        const int sub = tid & 3;
        for (int e = tid >> 2; e < tot; e += 64) {
            const int i = e / m_, j = e - i * m_;
            const int gr = T ? rowl[j] : rowl[i];
            const int gc = T ? coll[i] : coll[j];
            const float* p = d2p + gr * N + gc + sub * 16 * NN;
            float q0 = 0.f, q1 = 0.f, q2 = 0.f, q3 = 0.f;
            #pragma unroll
            for (int z = 0; z < 16; z += 4) {
                q0 += p[(z + 0) * NN]; q1 += p[(z + 1) * NN];
                q2 += p[(z + 2) * NN]; q3 += p[(z + 3) * NN];
            }
            float s = (q0 + q1) + (q2 + q3);
            s += __shfl_xor(s, 1, 64);
            s += __shfl_xor(s, 2, 64);
            if (sub == 0)
                sh.ncls[i * NSTR + j] = fmaxf(sqA_l[gr] + sqB_l[gc] - 2.f * s, 0.f);
        }
    }
    __syncthreads();

    double val = 0.0;
    if (shave && tid < 64) {
        const int lane = tid;
        const int n_ = sn, m_ = sm;
        const int W = (m_ <= 16) ? 16 : (m_ <= 32 ? 32 : 64);
        const bool cA = (lane < m_), rA = (lane < n_);

        double u = 0.0;
        if (rA) {
            float mx = 0.f;
            const float* row = &sh.ncls[lane * NSTR];
            for (int j = 0; j < m_; ++j) mx = fmaxf(mx, row[j]);
            u = -(double)mx;
        }
        double v = 1e30;
        for (int i = 0; i < n_; ++i) {
            double ui = __shfl(u, i, 64);
            if (cA) v = fmin(v, -(double)sh.ncls[i * NSTR + lane] - ui);
        }
        if (cA) clm[lane] = 0x7fffffff;
        wave_fence();
        int jc = -1;
        for (int j = 0; j < m_; ++j) {
            double vj = __shfl(v, j, 64);
            if (rA && jc < 0) {
                double s = -(double)sh.ncls[lane * NSTR + j] - u - vj;
                if (s < 1e-7) jc = j;
            }
        }
        if (rA && jc >= 0) atomicMin(&clm[jc], lane);
        wave_fence();
        int p = -1;
        if (cA && clm[lane] != 0x7fffffff) p = clm[lane];
        bool rowm = (rA && jc >= 0 && clm[jc] == lane);

        for (int ir = 0; ir < n_; ++ir) {
            if (__shfl(rowm ? 1 : 0, ir, 64)) continue;
            double minv = 1e30, markD = -1.0, ent = -1.0;
            bool used = false; int way = -2;
            if (rA && lane == ir) ent = 0.0;
            double D = 0.0;
            int i0 = ir, jprev = -1;
            int guard = 2 * m_ + 8;
            while (guard-- > 0) {
                double ui = __shfl(u, i0, 64);
                if (cA && !used) {
                    double cand = D - ui - (double)sh.ncls[i0 * NSTR + lane] - v;
                    if (cand < minv) { minv = cand; way = jprev; }
                }
                double kd = (cA && !used) ? embed_key(minv, lane) : 1e30;
                for (int oo = 1; oo < W; oo <<= 1) kd = fmin(kd, __shfl_xor(kd, oo, 64));
                long long kb = __double_as_longlong(kd);
                int j1 = (int)(kb & 127);
                double Dn = __longlong_as_double(kb & ~127LL);
                if (Dn > 1e29) break;
                D = Dn;
                int i1 = __shfl(p, j1, 64);
                if (i1 < 0) {
                    int jj = j1;
                    while (true) {
                        int wp = __shfl(way, jj, 64);
                        int pn = (wp < 0) ? ir : __shfl(p, wp, 64);
                        if (cA && lane == jj) p = pn;
                        if (wp < 0) break;
                        jj = wp;
                    }
                    if (rA && lane == ir) rowm = true;
                    break;
                }
                if (cA && lane == j1) { used = true; markD = D; }
                if (rA && lane == i1) ent = D;
                jprev = j1; i0 = i1;
            }
            if (rA && ent   >= 0.0) u += D - ent;
            if (cA && markD >= 0.0) v -= D - markD;
        }
        if (cA && p >= 0) val = (double)sh.ncls[p * NSTR + lane];
        #pragma unroll
        for (int oo = 1; oo < 64; oo <<= 1) val += __shfl_xor(val, oo, 64);
    }
    if (tid == 0) cls_val[blk] = val;

    // ---------------- Phase C: last-block finalize --------------------------
    __threadfence();
    if (tid == 0) {
        int old = atomicAdd(ctr, 1);
        isLast = (old == 63) ? 1 : 0;
    }
    __syncthreads();
    if (!isLast) return;
    __threadfence();

    if (tid < 64) { rcnt[tid] = 0; ccnt[tid] = 0; rcur[tid] = 0; ccur[tid] = 0; }
    if (tid == 0) { nbig_s = 0; flag_s = 0; big_total = 0.0; }
    if (tid < N)  { lbl1[tid] = t1[tid]; lbl2[tid] = t2[tid]; }
    __syncthreads();
    if (tid < 64 && flagarr[tid]) atomicOr(&flag_s, 1);
    if (tid < N) {
        atomicAdd(&rcnt[lbl1[tid] & 63], 1);
        atomicAdd(&ccnt[lbl2[tid] & 63], 1);
    }
    __syncthreads();
    if (tid < 64) {
        int rs_ = rcnt[tid], cs_ = ccnt[tid];
        #pragma unroll
        for (int oo = 1; oo < 64; oo <<= 1) {
            int tr = __shfl_up(rs_, oo, 64);
            int tc = __shfl_up(cs_, oo, 64);
            if (tid >= oo) { rs_ += tr; cs_ += tc; }
        }
        rstart[tid + 1] = rs_;
        cstart[tid + 1] = cs_;
        if (tid == 0) { rstart[0] = 0; cstart[0] = 0; }
        if (!flag_s) {
            int R = rcnt[tid], C = ccnt[tid];
            bool big = (R > 0) && (C > 0) && ((R > 64) || (C > 64));
            unsigned long long mb = __ballot(big);
            if (big) bigtasks[__popcll(mb & ((1ull << tid) - 1))] = tid;
            if (tid == 0) nbig_s = __popcll(mb);
        } else if (tid == 0) { nbig_s = 1; bigtasks[0] = -1; }
        double sv = flag_s ? 0.0 : cls_val[tid];
        #pragma unroll
        for (int oo = 1; oo < 64; oo <<= 1) sv += __shfl_xor(sv, oo, 64);
        if (tid == 0) small_sum = sv;
    }
    __syncthreads();

    const int nbig = nbig_s;
    if (nbig > 0) {
        if (tid < N) {
            int l1 = lbl1[tid] & 63;
            int p = atomicAdd(&rcur[l1], 1);
            rowlist[rstart[l1] + p] = tid;
            int l2 = lbl2[tid] & 63;
            int q = atomicAdd(&ccur[l2], 1);
            collist[cstart[l2] + q] = tid;
        }
        __syncthreads();
        #pragma unroll
        for (int pch = 0; pch < 64; ++pch) {
            int e = tid + pch * 256;
            int i = e >> 7, j = e & 127;
            sh.gml[i * GSTRIDE + j] = gm[rowlist[i] * N + collist[j]];
        }
        __syncthreads();

        for (int bt = 0; bt < nbig; ++bt) {
            const int c = bigtasks[bt];
            int Rn, Cn, rs, cs;
            if (c < 0) { Rn = N; Cn = N; rs = 0; cs = 0; }
            else { Rn = rcnt[c]; Cn = ccnt[c]; rs = rstart[c]; cs = cstart[c]; }
            const bool T = (Rn > Cn);
            const int n_ = T ? Cn : Rn, m_ = T ? Rn : Cn;
            const int rstep = T ? 1 : GSTRIDE;
            const int cstep = T ? GSTRIDE : 1;
            const int rb00 = T ? cs : rs * GSTRIDE;
            const int ob00 = T ? rs * GSTRIDE : cs;
            auto cost = [&](int i, int j) -> double {
                return -(double)sh.gml[rb00 + i * rstep + ob00 + j * cstep];
            };
            for (int x = tid; x <= m_; x += 256) { vbp[x] = 0.0; pb[x] = 0; }
            for (int x = tid; x <= n_; x += 256) { ub[x] = 0.0; }
            __syncthreads();
            for (int i = 1; i <= n_; ++i) {
                if (tid == 0) pb[0] = i;
                for (int x = tid; x <= m_; x += 256) { minvb[x] = 1e300; usedb[x] = 0; }
                __syncthreads();
                int j0 = 0;
                int guard = 2 * m_ + 8;
                while (guard-- > 0) {
                    if (tid == 0) usedb[j0] = 1;
                    __syncthreads();
                    const int i0 = pb[j0];
                    double dl = 1e300; int jl = 0;
                    if (tid < m_) {
                        int j = tid + 1;
                        if (!usedb[j]) {
                            double cur = cost(i0 - 1, j - 1) - ub[i0] - vbp[j];
                            if (cur < minvb[j]) { minvb[j] = cur; wayb[j] = j0; }
                            dl = minvb[j]; jl = j;
                        }
                    }
                    double rv = dl; int ri = jl;
                    #pragma unroll
                    for (int oo = 32; oo > 0; oo >>= 1) {
                        double ov = __shfl_down(rv, oo, 64);
                        int oi2 = __shfl_down(ri, oo, 64);
                        if (ov < rv) { rv = ov; ri = oi2; }
                    }
                    if ((tid & 63) == 0) { redv[tid >> 6] = rv; redi[tid >> 6] = ri; }
                    __syncthreads();
                    if (tid == 0) {
                        double bd = 1e300; int bj = 0;
                        for (int q = 0; q < NWF; ++q) if (redv[q] < bd) { bd = redv[q]; bj = redi[q]; }
                        redv[0] = bd; redi[0] = bj;
                    }
                    __syncthreads();
                    const double delta = redv[0];
                    const int j1 = redi[0];
                    if (tid < m_) {
                        int j = tid + 1;
                        if (usedb[j]) { ub[pb[j]] += delta; vbp[j] -= delta; }
                        else          { minvb[j] -= delta; }
                    }
                    if (tid == 0) ub[pb[0]] += delta;
                    __syncthreads();
                    j0 = j1;
                    if (pb[j0] == 0) break;
                }
                if (tid == 0) jfin_s = j0;
                __syncthreads();
                if (tid == 0) {
                    int jj = jfin_s;
                    while (jj) { int jp = wayb[jj]; pb[jj] = pb[jp]; jj = jp; }
                }
                __syncthreads();
            }
            double bl = 0.0;
            if (tid < m_) { int j = tid + 1; if (pb[j] != 0) bl = -cost(pb[j] - 1, j - 1); }
            #pragma unroll
            for (int oo = 32; oo > 0; oo >>= 1) bl += __shfl_down(bl, oo, 64);
            if ((tid & 63) == 0) redv[tid >> 6] = bl;
            __syncthreads();
            if (tid == 0) { double s = 0; for (int q = 0; q < NWF; ++q) s += redv[q]; big_total += s; }
            __syncthreads();
        }
    }

    if (tid == 0) out[0] = (float)((small_sum + big_total) / (double)N);
}

extern "C" void kernel_launch(void* const* d_in, const int* in_sizes, int n_in,
                              void* d_out, int out_size, void* d_ws, size_t ws_size,
                              hipStream_t stream) {
    const float* A  = (const float*)d_in[0];
    const float* B  = (const float*)d_in[1];
    const int*   t1 = (const int*)d_in[2];
    const int*   t2 = (const int*)d_in[3];
    float* out = (float*)d_out;
    float* d2p = (float*)d_ws;                        // [64][16384] dot partials, 4 MB
    float* gm  = d2p + ZSPLIT * NN;                   // [128][128] gm
    int*   flagarr = (int*)(gm + NN);                 // [64]
    double* cls_val = (double*)(flagarr + 64);        // [64] (8B aligned)
    float* sqAp = (float*)(cls_val + 64);             // [64][128] row-norm partials
    float* sqBp = sqAp + ZSPLIT * 128;                // [64][128] col-norm partials
    int*   ctr  = (int*)(sqBp + ZSPLIT * 128);        // done counter

    d2_partial<<<dim3(4, 4, ZSPLIT), 256, 0, stream>>>(A, B, d2p, sqAp, sqBp, ctr);
    reduce_solve<<<64, 256, 0, stream>>>(d2p, sqAp, sqBp, t1, t2, gm, flagarr,
                                         cls_val, ctr, out);
}

// Round 5
// 91.131 us; speedup vs baseline: 1.9869x; 1.0812x over previous
//
#include <hip/hip_runtime.h>

#define N 128
#define DIM 8192
#define NN (N * N)      // 16384
#define ZSPLIT 64
#define NW 16           // waves in finalize block
#define GSTRIDE 130     // LDS gm row stride (fallback solver)
#define NSTR 65         // per-class LDS row stride: 65%32=1 -> conflict-free col reads

// ---------------- wave-sync helpers ----------------------------------------
__device__ __forceinline__ void wave_fence() {
    __threadfence_block();
    __builtin_amdgcn_wave_barrier();
}
__device__ __forceinline__ double embed_key(double v, int j) {
    long long b = __double_as_longlong(v);
    return __longlong_as_double((b & ~127LL) | (long long)j);
}

// ---------------- Stage 1: dot partials + norm partials (split-K) -----------
// grid (4,4,64): 32x32 tile, K-chunk 128. 2x2 register tile per thread.
// Stores DOT products (1 fma/element instead of sub+fma); d2 assembled
// downstream as sqA + sqB - 2*dot. Norm partials from edge blocks.
__global__ __launch_bounds__(256) void d2_partial(const float* __restrict__ A,
                                                  const float* __restrict__ B,
                                                  float* __restrict__ d2p,
                                                  float* __restrict__ sqAp,
                                                  float* __restrict__ sqBp) {
    __shared__ float As[32][68];
    __shared__ float Bk[64][36];
    const int tid = threadIdx.x;
    const int bi = blockIdx.x, bj = blockIdx.y, bz = blockIdx.z;
    const int tx = tid & 15, ty = tid >> 4;
    const int row0 = bi * 32, col0 = bj * 32;
    const int kbase = bz * 128;

    // norm-partial prelude (edge blocks only, outside hot loop)
    if (bj == 0) {
        const int r = tid >> 3, seg = tid & 7;
        const float* pa = &A[(row0 + r) * DIM + kbase + seg * 16];
        float s = 0.f;
        #pragma unroll
        for (int u = 0; u < 4; ++u) {
            float4 v = *(const float4*)&pa[u * 4];
            s = fmaf(v.x, v.x, fmaf(v.y, v.y, fmaf(v.z, v.z, fmaf(v.w, v.w, s))));
        }
        #pragma unroll
        for (int o = 1; o < 8; o <<= 1) s += __shfl_xor(s, o, 64);
        if (seg == 0) sqAp[bz * 128 + row0 + r] = s;
    }
    if (bi == 0) {
        const int r = tid >> 3, seg = tid & 7;
        const float* pb = &B[(col0 + r) * DIM + kbase + seg * 16];
        float s = 0.f;
        #pragma unroll
        for (int u = 0; u < 4; ++u) {
            float4 v = *(const float4*)&pb[u * 4];
            s = fmaf(v.x, v.x, fmaf(v.y, v.y, fmaf(v.z, v.z, fmaf(v.w, v.w, s))));
        }
        #pragma unroll
        for (int o = 1; o < 8; o <<= 1) s += __shfl_xor(s, o, 64);
        if (seg == 0) sqBp[bz * 128 + col0 + r] = s;
    }

    float a00 = 0.f, a01 = 0.f, a10 = 0.f, a11 = 0.f;
    for (int it = 0; it < 2; ++it) {
        const int k0 = kbase + it * 64;
        __syncthreads();
        #pragma unroll
        for (int s = 0; s < 2; ++s) {
            int e = tid + s * 256;
            int r = e >> 4, q = e & 15;
            *(float4*)&As[r][q * 4] = *(const float4*)&A[(row0 + r) * DIM + k0 + q * 4];
        }
        #pragma unroll
        for (int s = 0; s < 2; ++s) {
            int r = tid & 31;
            int kq = (tid >> 5) + s * 8;
            float4 b4 = *(const float4*)&B[(col0 + r) * DIM + k0 + kq * 4];
            Bk[kq * 4 + 0][r] = b4.x;
            Bk[kq * 4 + 1][r] = b4.y;
            Bk[kq * 4 + 2][r] = b4.z;
            Bk[kq * 4 + 3][r] = b4.w;
        }
        __syncthreads();
        #pragma unroll
        for (int kk = 0; kk < 64; kk += 4) {
            float x0[4], x1[4];
            *(float4*)x0 = *(const float4*)&As[2 * ty][kk];
            *(float4*)x1 = *(const float4*)&As[2 * ty + 1][kk];
            float y[4][2];
            #pragma unroll
            for (int q = 0; q < 4; ++q)
                *(float2*)y[q] = *(const float2*)&Bk[kk + q][2 * tx];
            #pragma unroll
            for (int q = 0; q < 4; ++q) {
                a00 = fmaf(x0[q], y[q][0], a00);
                a01 = fmaf(x0[q], y[q][1], a01);
                a10 = fmaf(x1[q], y[q][0], a10);
                a11 = fmaf(x1[q], y[q][1], a11);
            }
        }
    }
    const int o0 = (row0 + 2 * ty) * N + col0 + 2 * tx;
    float* dst = d2p + bz * NN;
    *(float2*)&dst[o0]     = make_float2(a00, a01);
    *(float2*)&dst[o0 + N] = make_float2(a10, a11);
}

// ---------------- Stage 1.5: z-reduce + norm combine -> gm ------------------
__global__ __launch_bounds__(256) void reduce_gm(const float* __restrict__ d2p,
                                                 const float* __restrict__ sqAp,
                                                 const float* __restrict__ sqBp,
                                                 const int* __restrict__ t1,
                                                 const int* __restrict__ t2,
                                                 float* __restrict__ gm,
                                                 int* __restrict__ flagarr) {
    __shared__ float sqA_l[128], sqB_l[128];
    __shared__ int bf;
    const int tid = threadIdx.x;
    if (tid == 0) bf = 0;
    {   // stage reduced norm vectors
        const int c = tid & 127;
        const float* src = (tid < 128) ? (sqBp + c) : (sqAp + c);
        float t0 = 0.f, t1_ = 0.f, t2_ = 0.f, t3 = 0.f, t4 = 0.f, t5 = 0.f, t6 = 0.f, t7 = 0.f;
        #pragma unroll
        for (int z = 0; z < ZSPLIT; z += 8) {
            t0 += src[(z + 0) * 128]; t1_ += src[(z + 1) * 128];
            t2_ += src[(z + 2) * 128]; t3 += src[(z + 3) * 128];
            t4 += src[(z + 4) * 128]; t5 += src[(z + 5) * 128];
            t6 += src[(z + 6) * 128]; t7 += src[(z + 7) * 128];
        }
        float s = ((t0 + t1_) + (t2_ + t3)) + ((t4 + t5) + (t6 + t7));
        if (tid < 128) sqB_l[c] = s; else sqA_l[c] = s;
    }
    const int o = blockIdx.x * 256 + tid;
    float s0 = 0.f, s1 = 0.f, s2 = 0.f, s3 = 0.f, s4 = 0.f, s5 = 0.f, s6 = 0.f, s7 = 0.f;
    const float* p = d2p + o;
    #pragma unroll
    for (int z = 0; z < ZSPLIT; z += 8) {
        s0 += p[(z + 0) * NN]; s1 += p[(z + 1) * NN];
        s2 += p[(z + 2) * NN]; s3 += p[(z + 3) * NN];
        s4 += p[(z + 4) * NN]; s5 += p[(z + 5) * NN];
        s6 += p[(z + 6) * NN]; s7 += p[(z + 7) * NN];
    }
    float dot = ((s0 + s1) + (s2 + s3)) + ((s4 + s5) + (s6 + s7));
    __syncthreads();
    const int i = o >> 7, j = o & 127;
    const float s = sqA_l[i] + sqB_l[j] - 2.f * dot;
    const int l1 = t1[i], l2 = t2[j];
    const bool same = (l1 == l2);
    float g = same ? fmaxf(s, 0.f) : fmaxf(200.f - s, 0.f);
    gm[o] = g;
    bool bad = (!same && g > 0.f) || l1 < 0 || l1 > 63 || l2 < 0 || l2 > 63;
    unsigned long long m = __ballot(bad);
    if ((tid & 63) == 0 && m) atomicOr(&bf, 1);
    __syncthreads();
    if (tid == 0) flagarr[blockIdx.x] = bf;
}

// ---------------- Stage 2a: per-class Hungarian, one wave-block per class ---
__global__ __launch_bounds__(64) void solve_classes(const float* __restrict__ gm,
                                                    const int* __restrict__ flagarr,
                                                    const int* __restrict__ t1,
                                                    const int* __restrict__ t2,
                                                    double* __restrict__ cls_val) {
    __shared__ float ncls[64 * NSTR];   // 16.6 KB, row stride 65
    __shared__ int rowl[64], coll[64];
    __shared__ int rcnt[64], ccnt[64];
    __shared__ int tasks[64];
    __shared__ int clm[64];

    const int lane = threadIdx.x;
    const int l1a = t1[lane] & 63, l1b = t1[lane + 64] & 63;
    const int l2a = t2[lane] & 63, l2b = t2[lane + 64] & 63;
    const int fl  = flagarr[lane];
    rcnt[lane] = 0; ccnt[lane] = 0;
    __syncthreads();
    atomicAdd(&rcnt[l1a], 1); atomicAdd(&rcnt[l1b], 1);
    atomicAdd(&ccnt[l2a], 1); atomicAdd(&ccnt[l2b], 1);
    __syncthreads();
    const bool flag = (__ballot(fl != 0) != 0ull);
    int ntasks;
    {
        int R = rcnt[lane], C = ccnt[lane];
        bool small = (!flag) && (R > 0) && (C > 0) && (R <= 64) && (C <= 64);
        unsigned long long ms = __ballot(small);
        if (small) tasks[__popcll(ms & ((1ull << lane) - 1))] = lane;
        ntasks = (int)__popcll(ms);
    }
    __syncthreads();
    if ((int)blockIdx.x >= ntasks) {
        if (lane == 0) cls_val[blockIdx.x] = 0.0;
        return;
    }
    const int c = tasks[blockIdx.x];

    // compact this class's row/col index lists via ballots
    const unsigned long long mlt = (1ull << lane) - 1;
    unsigned long long b1 = __ballot(l1a == c);
    unsigned long long b2 = __ballot(l1b == c);
    if (l1a == c) rowl[__popcll(b1 & mlt)] = lane;
    if (l1b == c) rowl[__popcll(b1) + __popcll(b2 & mlt)] = lane + 64;
    const int Rn = (int)(__popcll(b1) + __popcll(b2));
    unsigned long long c1 = __ballot(l2a == c);
    unsigned long long c2 = __ballot(l2b == c);
    if (l2a == c) coll[__popcll(c1 & mlt)] = lane;
    if (l2b == c) coll[__popcll(c1) + __popcll(c2 & mlt)] = lane + 64;
    const int Cn = (int)(__popcll(c1) + __popcll(c2));
    __syncthreads();

    // stage normalized (n_ <= m_) class submatrix
    const bool T  = (Rn > Cn);
    const int n_  = T ? Cn : Rn;
    const int m_  = T ? Rn : Cn;
    const int tot = n_ * m_;
    for (int e = lane; e < tot; e += 64) {
        int i = e / m_, j = e - i * m_;
        int gr = T ? rowl[j] : rowl[i];
        int gc = T ? coll[i] : coll[j];
        ncls[i * NSTR + j] = gm[gr * N + gc];
    }
    __syncthreads();

    const int W = (m_ <= 16) ? 16 : (m_ <= 32 ? 32 : 64);
    const bool cA = (lane < m_), rA = (lane < n_);

    // row reduction: u = -max_j cls(row=lane, j)
    double u = 0.0;
    if (rA) {
        float mx = 0.f;
        const float* row = &ncls[lane * NSTR];
        for (int j = 0; j < m_; ++j) mx = fmaxf(mx, row[j]);
        u = -(double)mx;
    }
    // col reduction: v = min_i (-cls(i, col=lane) - u_i)
    double v = 1e30;
    for (int i = 0; i < n_; ++i) {
        double ui = __shfl(u, i, 64);
        if (cA) v = fmin(v, -(double)ncls[i * NSTR + lane] - ui);
    }
    // greedy tight assignment
    if (cA) clm[lane] = 0x7fffffff;
    wave_fence();
    int jc = -1;
    for (int j = 0; j < m_; ++j) {
        double vj = __shfl(v, j, 64);
        if (rA && jc < 0) {
            double s = -(double)ncls[lane * NSTR + j] - u - vj;
            if (s < 1e-7) jc = j;
        }
    }
    if (rA && jc >= 0) atomicMin(&clm[jc], lane);
    wave_fence();
    int p = -1;
    if (cA && clm[lane] != 0x7fffffff) p = clm[lane];
    bool rowm = (rA && jc >= 0 && clm[jc] == lane);

    // augmentation phases (JV)
    for (int ir = 0; ir < n_; ++ir) {
        if (__shfl(rowm ? 1 : 0, ir, 64)) continue;
        double minv = 1e30, markD = -1.0, ent = -1.0;
        bool used = false; int way = -2;
        if (rA && lane == ir) ent = 0.0;
        double D = 0.0;
        int i0 = ir, jprev = -1;
        int guard = 2 * m_ + 8;
        while (guard-- > 0) {
            double ui = __shfl(u, i0, 64);
            if (cA && !used) {
                double cand = D - ui - (double)ncls[i0 * NSTR + lane] - v;
                if (cand < minv) { minv = cand; way = jprev; }
            }
            double kd = (cA && !used) ? embed_key(minv, lane) : 1e30;
            for (int o = 1; o < W; o <<= 1) kd = fmin(kd, __shfl_xor(kd, o, 64));
            long long kb = __double_as_longlong(kd);
            int j1 = (int)(kb & 127);
            double Dn = __longlong_as_double(kb & ~127LL);
            if (Dn > 1e29) break;
            D = Dn;
            int i1 = __shfl(p, j1, 64);
            if (i1 < 0) {                 // free col: augment along way[]
                int jj = j1;
                while (true) {
                    int wp = __shfl(way, jj, 64);
                    int pn = (wp < 0) ? ir : __shfl(p, wp, 64);
                    if (cA && lane == jj) p = pn;
                    if (wp < 0) break;
                    jj = wp;
                }
                if (rA && lane == ir) rowm = true;
                break;
            }
            if (cA && lane == j1) { used = true; markD = D; }
            if (rA && lane == i1) ent = D;
            jprev = j1; i0 = i1;
        }
        if (rA && ent   >= 0.0) u += D - ent;
        if (cA && markD >= 0.0) v -= D - markD;
    }

    // class value
    double val = 0.0;
    if (cA && p >= 0) val = (double)ncls[p * NSTR + lane];
    #pragma unroll
    for (int o = 1; o < 64; o <<= 1) val += __shfl_xor(val, o, 64);
    if (lane == 0) cls_val[blockIdx.x] = val;
}

// ---------------- Stage 2b: sum class values + rare block-wide fallback -----
__global__ __launch_bounds__(1024) void finalize_kernel(const float* __restrict__ gm,
                                                        const int* __restrict__ flagarr,
                                                        const int* __restrict__ t1,
                                                        const int* __restrict__ t2,
                                                        const double* __restrict__ cls_val,
                                                        float* __restrict__ out) {
    __shared__ float gml[N * GSTRIDE];
    __shared__ int lbl1[N], lbl2[N];
    __shared__ int rowlist[N], collist[N];
    __shared__ int rcnt[64], ccnt[64], rstart[65], cstart[65], rcur[64], ccur[64];
    __shared__ int bigtasks[65];
    __shared__ int nbig_s, flag_s;
    __shared__ double ub[N + 1], vbp[N + 1], minvb[N + 1];
    __shared__ int pb[N + 1], wayb[N + 1], usedb[N + 1];
    __shared__ double redv[NW];
    __shared__ int redi[NW];
    __shared__ double big_total, small_sum;
    __shared__ int jfin_s;

    const int tid = threadIdx.x;
    if (tid < 64) { rcnt[tid] = 0; ccnt[tid] = 0; rcur[tid] = 0; ccur[tid] = 0; }
    if (tid == 0) { nbig_s = 0; flag_s = 0; big_total = 0.0; }
    if (tid < N)  { lbl1[tid] = t1[tid]; lbl2[tid] = t2[tid]; }
    __syncthreads();
    if (tid < 64 && flagarr[tid]) atomicOr(&flag_s, 1);
    if (tid < N) {
        atomicAdd(&rcnt[lbl1[tid] & 63], 1);
        atomicAdd(&ccnt[lbl2[tid] & 63], 1);
    }
    double sv = (tid < 64) ? cls_val[tid] : 0.0;
    __syncthreads();
    if (tid < 64) {
        int rs_ = rcnt[tid], cs_ = ccnt[tid];
        #pragma unroll
        for (int o = 1; o < 64; o <<= 1) {
            int tr = __shfl_up(rs_, o, 64);
            int tc = __shfl_up(cs_, o, 64);
            if (tid >= o) { rs_ += tr; cs_ += tc; }
        }
        rstart[tid + 1] = rs_;
        cstart[tid + 1] = cs_;
        if (tid == 0) { rstart[0] = 0; cstart[0] = 0; }
        if (!flag_s) {
            int R = rcnt[tid], C = ccnt[tid];
            bool big = (R > 0) && (C > 0) && ((R > 64) || (C > 64));
            unsigned long long mb = __ballot(big);
            if (big) bigtasks[__popcll(mb & ((1ull << tid) - 1))] = tid;
            if (tid == 0) nbig_s = __popcll(mb);
        } else if (tid == 0) { nbig_s = 1; bigtasks[0] = -1; }
        if (flag_s) sv = 0.0;
        #pragma unroll
        for (int o = 1; o < 64; o <<= 1) sv += __shfl_xor(sv, o, 64);
        if (tid == 0) small_sum = sv;
    }
    __syncthreads();

    const int nbig = nbig_s;
    if (nbig > 0) {
        if (tid < N) {       // counting-sort scatter
            int l1 = lbl1[tid] & 63;
            int p = atomicAdd(&rcur[l1], 1);
            rowlist[rstart[l1] + p] = tid;
            int l2 = lbl2[tid] & 63;
            int q = atomicAdd(&ccur[l2], 1);
            collist[cstart[l2] + q] = tid;
        }
        __syncthreads();
        #pragma unroll
        for (int pch = 0; pch < 16; ++pch) {
            int e = tid + pch * 1024;
            int i = e >> 7, j = e & 127;
            gml[i * GSTRIDE + j] = gm[rowlist[i] * N + collist[j]];
        }
        __syncthreads();

        for (int bt = 0; bt < nbig; ++bt) {
            const int c = bigtasks[bt];
            int Rn, Cn, rs, cs;
            if (c < 0) { Rn = N; Cn = N; rs = 0; cs = 0; }
            else { Rn = rcnt[c]; Cn = ccnt[c]; rs = rstart[c]; cs = cstart[c]; }
            const bool T = (Rn > Cn);
            const int n_ = T ? Cn : Rn, m_ = T ? Rn : Cn;
            const int rstep = T ? 1 : GSTRIDE;
            const int cstep = T ? GSTRIDE : 1;
            const int rb00 = T ? cs : rs * GSTRIDE;
            const int ob00 = T ? rs * GSTRIDE : cs;
            auto cost = [&](int i, int j) -> double {
                return -(double)gml[rb00 + i * rstep + ob00 + j * cstep];
            };
            for (int x = tid; x <= m_; x += 1024) { vbp[x] = 0.0; pb[x] = 0; }
            for (int x = tid; x <= n_; x += 1024) { ub[x] = 0.0; }
            __syncthreads();
            for (int i = 1; i <= n_; ++i) {
                if (tid == 0) pb[0] = i;
                for (int x = tid; x <= m_; x += 1024) { minvb[x] = 1e300; usedb[x] = 0; }
                __syncthreads();
                int j0 = 0;
                int guard = 2 * m_ + 8;
                while (guard-- > 0) {
                    if (tid == 0) usedb[j0] = 1;
                    __syncthreads();
                    const int i0 = pb[j0];
                    double dl = 1e300; int jl = 0;
                    if (tid < m_) {
                        int j = tid + 1;
                        if (!usedb[j]) {
                            double cur = cost(i0 - 1, j - 1) - ub[i0] - vbp[j];
                            if (cur < minvb[j]) { minvb[j] = cur; wayb[j] = j0; }
                            dl = minvb[j]; jl = j;
                        }
                    }
                    double rv = dl; int ri = jl;
                    #pragma unroll
                    for (int o = 32; o > 0; o >>= 1) {
                        double ov = __shfl_down(rv, o, 64);
                        int oi2 = __shfl_down(ri, o, 64);
                        if (ov < rv) { rv = ov; ri = oi2; }
                    }
                    if ((tid & 63) == 0) { redv[tid >> 6] = rv; redi[tid >> 6] = ri; }
                    __syncthreads();
                    if (tid == 0) {
                        double bd = 1e300; int bj = 0;
                        for (int q = 0; q < NW; ++q) if (redv[q] < bd) { bd = redv[q]; bj = redi[q]; }
                        redv[0] = bd; redi[0] = bj;
                    }
                    __syncthreads();
                    const double delta = redv[0];
                    const int j1 = redi[0];
                    if (tid < m_) {
                        int j = tid + 1;
                        if (usedb[j]) { ub[pb[j]] += delta; vbp[j] -= delta; }
                        else          { minvb[j] -= delta; }
                    }
                    if (tid == 0) ub[pb[0]] += delta;
                    __syncthreads();
                    j0 = j1;
                    if (pb[j0] == 0) break;
                }
                if (tid == 0) jfin_s = j0;
                __syncthreads();
                if (tid == 0) {
                    int jj = jfin_s;
                    while (jj) { int jp = wayb[jj]; pb[jj] = pb[jp]; jj = jp; }
                }
                __syncthreads();
            }
            double bl = 0.0;
            if (tid < m_) { int j = tid + 1; if (pb[j] != 0) bl = -cost(pb[j] - 1, j - 1); }
            #pragma unroll
            for (int o = 32; o > 0; o >>= 1) bl += __shfl_down(bl, o, 64);
            if ((tid & 63) == 0) redv[tid >> 6] = bl;
            __syncthreads();
            if (tid == 0) { double s = 0; for (int q = 0; q < NW; ++q) s += redv[q]; big_total += s; }
            __syncthreads();
        }
    }

    if (tid == 0) out[0] = (float)((small_sum + big_total) / (double)N);
}

extern "C" void kernel_launch(void* const* d_in, const int* in_sizes, int n_in,
                              void* d_out, int out_size, void* d_ws, size_t ws_size,
                              hipStream_t stream) {
    const float* A  = (const float*)d_in[0];
    const float* B  = (const float*)d_in[1];
    const int*   t1 = (const int*)d_in[2];
    const int*   t2 = (const int*)d_in[3];
    float* out = (float*)d_out;
    float* d2p = (float*)d_ws;                        // [64][16384] dot partials, 4 MB
    float* gm  = d2p + ZSPLIT * NN;                   // [128][128] gm
    int*   flagarr = (int*)(gm + NN);                 // [64]
    double* cls_val = (double*)(flagarr + 64);        // [64] (8B aligned)
    float* sqAp = (float*)(cls_val + 64);             // [64][128] row-norm partials
    float* sqBp = sqAp + ZSPLIT * 128;                // [64][128] col-norm partials

    d2_partial<<<dim3(4, 4, ZSPLIT), 256, 0, stream>>>(A, B, d2p, sqAp, sqBp);
    reduce_gm<<<64, 256, 0, stream>>>(d2p, sqAp, sqBp, t1, t2, gm, flagarr);
    solve_classes<<<64, 64, 0, stream>>>(gm, flagarr, t1, t2, cls_val);
    finalize_kernel<<<1, 1024, 0, stream>>>(gm, flagarr, t1, t2, cls_val, out);
}